// Round 9
// baseline (239.148 us; speedup 1.0000x reference)
//
#include <hip/hip_runtime.h>
#include <stdint.h>

// Causal depthwise conv1d: y[b,s,h] = sum_j x[b,s-3+j,h] * w[h,j], * mask[b,s]
// B=4, S=4096, H=2048, K=4, fp32.
//
// Machine model (R3..R11): every 1R+1W structure = 79-83us (~2.5 TB/s HBM);
// copy serves ~2x per direction. Root cause: register-resident prefetch is
// always collapsed by the allocator (R6 ring, R8 batch, R11 dbuf: VGPR stayed
// 32/60 => 1 load in flight). R12: global_load_lds DMA -- loads have NO dest
// register, so the allocator cannot serialize them; HW queue holds them; wave
// waits only at counted vmcnt (m201 T3+T4 pattern: never vmcnt(0) in-loop,
// raw s_barrier without drain).
// Block = 32 rows, 8 tiles x 4 rows (32KiB), 2 LDS bufs = 64KiB -> 2 blocks/CU.
// Predict: dur 50-62us, BW>=3.4 TB/s, LDS 65536, VGPR 60-80, WRITE ~131MB.
// Failure sigs: WRITE ~470MB => R10 LDS write-amp real; dur ~79 => roofline.

constexpr int B_    = 4;
constexpr int S_    = 4096;
constexpr int H_    = 2048;
constexpr int H4    = H_ / 4;            // 512 float4 per row
constexpr int TPB   = 512;               // thread t == column h4
constexpr int TROWS = 4;                 // rows per tile
constexpr int TILE4 = TROWS * H4;        // 2048 float4 = 32 KiB
constexpr int SPANR = 32;                // rows per block
constexpr int NT    = SPANR / TROWS;     // 8 tiles per block
constexpr int NBLK  = B_ * S_ / SPANR;   // 512 blocks (2 per CU)

typedef float f32x4 __attribute__((ext_vector_type(4)));

// Stage one 4-row tile into LDS via direct DMA. Per wave: 4 ops x 64 lanes x
// 16B = 4KB. LDS dest is wave-uniform base; HW writes base + lane*16 (m104),
// matching the per-lane global addr gsrc + fo + ln -> linear layout.
__device__ __forceinline__ void stage_tile(const float4* gsrc, float4* lbuf,
                                           int wv, int ln) {
    #pragma unroll
    for (int j = 0; j < 4; ++j) {
        const int fo = (wv * 4 + j) * 64;            // float4 offset of chunk
        __builtin_amdgcn_global_load_lds(
            (const __attribute__((address_space(1))) void*)(gsrc + fo + ln),
            (__attribute__((address_space(3))) void*)(lbuf + fo),
            16, 0, 0);
    }
}

__device__ __forceinline__ f32x4 conv_row(const float4& x3, const float4& x2,
                                          const float4& x1, const float4& x0,
                                          const float4& w0, const float4& w1,
                                          const float4& w2, const float4& w3,
                                          float m) {
    f32x4 o;
    o.x = fmaf(x3.x, w0.x, fmaf(x2.x, w0.y, fmaf(x1.x, w0.z, x0.x * w0.w)));
    o.y = fmaf(x3.y, w1.x, fmaf(x2.y, w1.y, fmaf(x1.y, w1.z, x0.y * w1.w)));
    o.z = fmaf(x3.z, w2.x, fmaf(x2.z, w2.y, fmaf(x1.z, w2.z, x0.z * w2.w)));
    o.w = fmaf(x3.w, w3.x, fmaf(x2.w, w3.y, fmaf(x1.w, w3.z, x0.w * w3.w)));
    o.x *= m; o.y *= m; o.z *= m; o.w *= m;
    return o;
}

__global__ __launch_bounds__(TPB, 4) void budgie_dwconv1d_kernel(
    const float* __restrict__ x,     // [B,S,H]
    const float* __restrict__ w,     // [H,K]
    const float* __restrict__ mask,  // [B,S]
    float* __restrict__ y)           // [B,S,H]
{
    __shared__ float4 buf[2][TILE4];                 // 64 KiB -> 2 blocks/CU

    const int t  = threadIdx.x;                      // column h4, 0..511
    const int wv = t >> 6;                           // wave id 0..7
    const int ln = t & 63;                           // lane id
    const int r0 = blockIdx.x * SPANR;               // first row of span

    const float4* x4 = (const float4*)x;
    const float4* w4 = (const float4*)w;
    f32x4* y4 = (f32x4*)y;

    // Per-channel taps (column t loop-invariant).
    const float4 w0 = w4[t * 4 + 0];
    const float4 w1 = w4[t * 4 + 1];
    const float4 w2 = w4[t * 4 + 2];
    const float4 w3 = w4[t * 4 + 3];

    const float4 zero4 = make_float4(0.f, 0.f, 0.f, 0.f);

    // Halo registers: columns of rows r0-1, r0-2, r0-3 (hk = row r0-k).
    float4 h1, h2, h3;
    if (r0 >= 3) {                                   // only block 0 lacks them
        h1 = x4[(long)(r0 - 1) * H4 + t];
        h2 = x4[(long)(r0 - 2) * H4 + t];
        h3 = x4[(long)(r0 - 3) * H4 + t];
    } else {
        h1 = h2 = h3 = zero4;
    }

    // Prologue: DMA tile 0; one-time full drain (also covers halo loads).
    stage_tile(x4 + (long)r0 * H4, buf[0], wv, ln);
    asm volatile("s_waitcnt vmcnt(0)" ::: "memory");
    __builtin_amdgcn_sched_barrier(0);
    __builtin_amdgcn_s_barrier();

    for (int i = 0; i < NT; ++i) {
        const int R = r0 + i * TROWS;
        const int p = i & 1;

        // (1) Fire-and-forget DMA for tile i+1 into the other buffer.
        //     Safe: end-barrier of iter i-1 guaranteed all reads of it done.
        if (i + 1 < NT) {
            stage_tile(x4 + (long)(R + TROWS) * H4, buf[1 - p], wv, ln);
            // (2) Counted wait: tile-i DMAs retired. Newer ops allowed in
            //     flight: 4 stores(i-1) + 4 DMA(i+1) = 8. Never drain to 0.
            asm volatile("s_waitcnt vmcnt(8)" ::: "memory");
        } else {
            // Last tile: only 4 stores(i-1) are newer than tile-i DMAs.
            asm volatile("s_waitcnt vmcnt(4)" ::: "memory");
        }
        __builtin_amdgcn_sched_barrier(0);
        __builtin_amdgcn_s_barrier();                // buf[p] valid for all waves

        // (3) Taps from LDS (contiguous ds_read_b128, conflict-free).
        const float4 L0 = buf[p][0 * H4 + t];
        const float4 L1 = buf[p][1 * H4 + t];
        const float4 L2 = buf[p][2 * H4 + t];
        const float4 L3 = buf[p][3 * H4 + t];

        // Batch start: halo regs represent pre-batch rows exclusively -> zero.
        if ((R & (S_ - 1)) == 0) { h1 = h2 = h3 = zero4; }

        const int Ru = __builtin_amdgcn_readfirstlane(R);  // mask via s_load

        f32x4 o0 = conv_row(h3, h2, h1, L0, w0, w1, w2, w3, mask[Ru + 0]);
        f32x4 o1 = conv_row(h2, h1, L0, L1, w0, w1, w2, w3, mask[Ru + 1]);
        f32x4 o2 = conv_row(h1, L0, L1, L2, w0, w1, w2, w3, mask[Ru + 2]);
        f32x4 o3 = conv_row(L0, L1, L2, L3, w0, w1, w2, w3, mask[Ru + 3]);

        __builtin_nontemporal_store(o0, y4 + (long)(R + 0) * H4 + t);
        __builtin_nontemporal_store(o1, y4 + (long)(R + 1) * H4 + t);
        __builtin_nontemporal_store(o2, y4 + (long)(R + 2) * H4 + t);
        __builtin_nontemporal_store(o3, y4 + (long)(R + 3) * H4 + t);

        // (4) Rotate halo for next tile (rows R+1..R+3 already in registers).
        h1 = L3; h2 = L2; h3 = L1;

        // (5) All waves done reading buf[p] before iter i+1 DMAs into buf[1-p]
        //     and (at i+2) into buf[p]. No vmcnt drain here.
        __builtin_amdgcn_s_barrier();
    }
}

extern "C" void kernel_launch(void* const* d_in, const int* in_sizes, int n_in,
                              void* d_out, int out_size, void* d_ws, size_t ws_size,
                              hipStream_t stream) {
    const float* x    = (const float*)d_in[0];   // hidden_states [B,S,H]
    const float* w    = (const float*)d_in[1];   // weight [H,K]
    const float* mask = (const float*)d_in[2];   // attention_mask_2d [B,S]
    float* y = (float*)d_out;

    budgie_dwconv1d_kernel<<<dim3(NBLK), TPB, 0, stream>>>(x, w, mask, y);
}